// Round 9
// baseline (135.773 us; speedup 1.0000x reference)
//
#include <hip/hip_runtime.h>
#include <math.h>

#define NPTS 4096
#define NSMP 10

typedef float f32x2 __attribute__((ext_vector_type(2)));

// ---------------- prep: fuse (w1,b1,w2,b2) -> Wn[30][64] ([s*3+c][p]), bb[64] ----------
// out[p] = bb[p] + sum_{s,c} Wn[s*3+c][p] * pos[b,c,idx_s]  (no nonlinearity -> legal).
__global__ __launch_bounds__(256) void prep_kernel(
    const float* __restrict__ w1, const float* __restrict__ b1,
    const float* __restrict__ w2, const float* __restrict__ b2,
    float* __restrict__ wn, float* __restrict__ bb) {
  __shared__ float w1l[64 * 48];      // 12 KB, [o][k]
  __shared__ float w2t[64 * 64];      // 16 KB, transposed [o][p] (lane reads stride-1)
  __shared__ float b1l[64];
  __shared__ float part[4][30][64];   // 30 KB
  __shared__ float bpart[4][64];
  const int t = threadIdx.x, p = t & 63, grp = t >> 6, o0 = grp * 16;
  for (int idx = t; idx < 64 * 48; idx += 256) w1l[idx] = w1[idx];
  for (int idx = t; idx < 64 * 64; idx += 256) w2t[(idx & 63) * 64 + (idx >> 6)] = w2[idx];
  if (t < 64) b1l[t] = b1[t];
  __syncthreads();

  const int sg[16] = {0,2,4,6, 3,5,7,9, 1,3,5,7, 2,4,6,8};
  float w2r[16];
  #pragma unroll
  for (int oo = 0; oo < 16; ++oo) w2r[oo] = w2t[(o0 + oo) * 64 + p];
  float wloc[30];
  #pragma unroll
  for (int i = 0; i < 30; ++i) wloc[i] = 0.0f;
  #pragma unroll
  for (int g = 0; g < 4; ++g)
    #pragma unroll
    for (int i = 0; i < 2; ++i)
      #pragma unroll
      for (int j = 0; j < 2; ++j) {
        const int s = sg[g * 4 + i * 2 + j];
        #pragma unroll
        for (int c = 0; c < 3; ++c) {
          const int k = (c + 3 * g) * 4 + i * 2 + j;   // w1 flat index over (12,2,2)
          float wk = 0.0f;
          #pragma unroll
          for (int oo = 0; oo < 16; ++oo)
            wk = fmaf(w2r[oo], w1l[(o0 + oo) * 48 + k], wk);  // w1l read is broadcast
          wloc[s * 3 + c] += wk;
        }
      }
  #pragma unroll
  for (int i = 0; i < 30; ++i) part[grp][i][p] = wloc[i];
  float sb = 0.0f;
  #pragma unroll
  for (int oo = 0; oo < 16; ++oo) sb = fmaf(w2r[oo], b1l[o0 + oo], sb);
  bpart[grp][p] = sb;
  __syncthreads();
  const float* p0 = &part[0][0][0];
  for (int idx = t; idx < 30 * 64; idx += 256)
    wn[idx] = p0[idx] + p0[1920 + idx] + p0[3840 + idx] + p0[5760 + idx];
  if (t < 64) bb[t] = b2[t] + bpart[0][t] + bpart[1][t] + bpart[2][t] + bpart[3][t];
}

// ---------------- fused topk + mlp, 2-blocks/CU, spill-free edition -------------------
// 1024 threads (16 waves), grid 64x8 = 512 blocks. LDS 74.75 KB -> HW caps at 2
// blocks/CU (149.5 <= 160 KB); that alone gives 32 waves/CU. __launch_bounds__ is
// (1024, 4): on this compiler the VGPR budget empirically = 256/waves_arg
// ((_,2)->88-92, (_,4)->64, (_,8)->32 across R3-R8), so 4 -> 64-VGPR budget, which
// this body fits WITHOUT spilling (R7/R8's (1024,8) forced 32 VGPRs -> ~25
// dwords/thread scratch = the flat 47 MB WRITE + 21 MB FETCH).
//   * tau via MSB-first radix-select: prefix is wave-uniform -> SGPRs.
//     T = pfx|0xFF >= 10th-smallest lane-min -> valid upper bound on the row's
//     10th-smallest key; slack covers f32-vs-f64.
// Selection semantics (key formula both passes, slack, f64 re-rank) unchanged
// from R6/R7/R8 -> bit-identical output.
__global__ __launch_bounds__(1024, 4) void topk_kernel(const float* __restrict__ pos,
                                                       const float* __restrict__ wng,
                                                       const float* __restrict__ bbg,
                                                       float* __restrict__ out) {
  __shared__ float pts3[NPTS * 3];    // 48 KB packed (x,y,z)
  __shared__ float trans[16 * 260];   // 16.25 KB; per-wave 260-float slice (alias: bufi)
  __shared__ float wl[30 * 64];       // 7.5 KB Wn
  __shared__ float bl[64];
  __shared__ int   nbrL[16][4][NSMP]; // 2.5 KB
  __shared__ int   cnt[16][4];

  const int b = blockIdx.y, tid = threadIdx.x, lane = tid & 63, wv = tid >> 6;
  const float* pb = pos + (size_t)b * 3 * NPTS;
  for (int i = tid; i < NPTS; i += 1024) {
    pts3[3 * i + 0] = pb[i];
    pts3[3 * i + 1] = pb[i + NPTS];
    pts3[3 * i + 2] = pb[i + 2 * NPTS];
  }
  for (int i = tid; i < 30 * 64; i += 1024) wl[i] = wng[i];
  if (tid < 64) bl[tid] = bbg[tid];
  __syncthreads();

  const int nb = blockIdx.x * 64;       // block's first row
  const int n0 = nb + wv * 4;           // wave's first row
  float* transF = &trans[wv * 260];     // this wave's private slice
  int*   bufiW  = (int*)transF;         // survivor buffer: r*64+slot (256 ints <= 260)

  // 4 queries, pair-packed, -2 folded (filter-only arithmetic)
  f32x2 qx2[2], qy2[2], qz2[2], dmin[2];
  #pragma unroll
  for (int pp = 0; pp < 2; ++pp) {
    int na = n0 + 2 * pp;
    qx2[pp].x = -2.0f * pts3[3 * na + 0]; qx2[pp].y = -2.0f * pts3[3 * na + 3];
    qy2[pp].x = -2.0f * pts3[3 * na + 1]; qy2[pp].y = -2.0f * pts3[3 * na + 4];
    qz2[pp].x = -2.0f * pts3[3 * na + 2]; qz2[pp].y = -2.0f * pts3[3 * na + 5];
    dmin[pp].x = INFINITY; dmin[pp].y = INFINITY;
  }

  // ---- pass 1: per-row lane minima ----
  #pragma unroll 2
  for (int k = 0; k < 64; ++k) {
    int m = k * 64 + lane;
    float x = pts3[3 * m], y = pts3[3 * m + 1], z = pts3[3 * m + 2];
    float sq = fmaf(z, z, fmaf(y, y, x * x));
    f32x2 sq2; sq2.x = sq; sq2.y = sq;
    #pragma unroll
    for (int pp = 0; pp < 2; ++pp) {
      f32x2 key = qx2[pp] * x + sq2;
      key = qy2[pp] * y + key;
      key = qz2[pp] * z + key;
      dmin[pp] = __builtin_elementwise_min(dmin[pp], key);
    }
  }

  // ---- tau: MSB-first radix-select; prefix is wave-uniform (SGPRs) ----
  unsigned um[4];
  #pragma unroll
  for (int r = 0; r < 4; ++r) {
    float dm = (r & 1) ? dmin[r >> 1].y : dmin[r >> 1].x;
    unsigned ub = __float_as_uint(dm);
    um[r] = (ub & 0x80000000u) ? ~ub : (ub | 0x80000000u);
  }
  unsigned pfx0 = 0u, pfx1 = 0u, pfx2 = 0u, pfx3 = 0u;
  #pragma unroll 1
  for (int bno = 31; bno >= 8; --bno) {
    const unsigned bit = 1u << bno, ones = bit - 1u;
    if (__popcll(__ballot(um[0] <= (pfx0 | ones))) < NSMP) pfx0 |= bit;
    if (__popcll(__ballot(um[1] <= (pfx1 | ones))) < NSMP) pfx1 |= bit;
    if (__popcll(__ballot(um[2] <= (pfx2 | ones))) < NSMP) pfx2 |= bit;
    if (__popcll(__ballot(um[3] <= (pfx3 | ones))) < NSMP) pfx3 |= bit;
  }
  float tx[4];
  #pragma unroll
  for (int r = 0; r < 4; ++r) {
    unsigned T = ((r == 0) ? pfx0 : (r == 1) ? pfx1 : (r == 2) ? pfx2 : pfx3) | 0xFFu;
    unsigned tb = (T & 0x80000000u) ? (T ^ 0x80000000u) : ~T;
    float tf = __uint_as_float(tb);
    tx[r] = __fadd_rn(__fadd_rn(tf, 2e-4f), __fmul_rn(fabsf(tf), 1e-5f));
  }

  if (lane < 4) cnt[wv][lane] = 0;     // same-wave DS ops are in-order

  // ---- pass 2: recompute keys (identical formula), push survivors ----
  #pragma unroll 2
  for (int k = 0; k < 64; ++k) {
    int m = k * 64 + lane;
    float x = pts3[3 * m], y = pts3[3 * m + 1], z = pts3[3 * m + 2];
    float sq = fmaf(z, z, fmaf(y, y, x * x));
    f32x2 sq2; sq2.x = sq; sq2.y = sq;
    #pragma unroll
    for (int pp = 0; pp < 2; ++pp) {
      f32x2 key = qx2[pp] * x + sq2;
      key = qy2[pp] * y + key;
      key = qz2[pp] * z + key;
      if (key.x <= tx[2 * pp]) {
        int ps = atomicAdd(&cnt[wv][2 * pp], 1);
        if (ps < 64) bufiW[(2 * pp) * 64 + ps] = m;
      }
      if (key.y <= tx[2 * pp + 1]) {
        int ps = atomicAdd(&cnt[wv][2 * pp + 1], 1);
        if (ps < 64) bufiW[(2 * pp + 1) * 64 + ps] = m;
      }
    }
  }

  // ---- pass 3: f64 re-rank via readlane rank-count, j-major ----
  int c[4], si[4], rank[4];
  double dd[4];
  int cmax = 0;
  #pragma unroll
  for (int r = 0; r < 4; ++r) {
    c[r] = __builtin_amdgcn_readfirstlane(cnt[wv][r]);
    if (c[r] > 64) c[r] = 64;
    cmax = (c[r] > cmax) ? c[r] : cmax;
    rank[r] = 0;
  }
  #pragma unroll
  for (int r = 0; r < 4; ++r) {
    int nq = n0 + r;
    float qxf = pts3[3 * nq], qyf = pts3[3 * nq + 1], qzf = pts3[3 * nq + 2];
    if (lane < c[r]) {
      si[r] = bufiW[r * 64 + lane];
      float px = pts3[3 * si[r]], py = pts3[3 * si[r] + 1], pz = pts3[3 * si[r] + 2];
      double dqx = (double)qxf, dqy = (double)qyf, dqz = (double)qzf;
      double dpx = (double)px, dpy = (double)py, dpz = (double)pz;
      double dot = dqx * dpx + dqy * dpy + dqz * dpz;
      double sqn = dqx * dqx + dqy * dqy + dqz * dqz;
      double sqm = dpx * dpx + dpy * dpy + dpz * dpz;
      dd[r] = (sqn - 2.0 * dot) + sqm;             // self -> exactly 0.0
    } else { dd[r] = (double)INFINITY; si[r] = 0x7FFFFFFF; }
  }
  #pragma unroll 1
  for (int j = 0; j < cmax; ++j) {
    #pragma unroll
    for (int r = 0; r < 4; ++r) {
      int jlo = __builtin_amdgcn_readlane(__double2loint(dd[r]), j);
      int jhi = __builtin_amdgcn_readlane(__double2hiint(dd[r]), j);
      int ji  = __builtin_amdgcn_readlane(si[r], j);
      double jd = __hiloint2double(jhi, jlo);
      if (jd < dd[r] || (jd == dd[r] && ji < si[r])) ++rank[r];
    }
  }
  #pragma unroll
  for (int r = 0; r < 4; ++r)
    if (lane < c[r] && rank[r] < NSMP)
      nbrL[wv][r][rank[r]] = si[r];

  // ---- epilogue: acc then per-wave transpose slice (bufiW is dead now) ----
  #pragma unroll 1
  for (int r = 0; r < 4; ++r) {
    float a = bl[lane];
    #pragma unroll
    for (int s = 0; s < NSMP; ++s) {
      int id = nbrL[wv][r][s];          // uniform -> broadcast ds_read
      float px = pts3[3 * id], py = pts3[3 * id + 1], pz = pts3[3 * id + 2];
      a = fmaf(wl[(s * 3 + 0) * 64 + lane], px, a);
      a = fmaf(wl[(s * 3 + 1) * 64 + lane], py, a);
      a = fmaf(wl[(s * 3 + 2) * 64 + lane], pz, a);
    }
    transF[r * 65 + lane] = a;          // padded row -> conflict-free
  }
  __syncthreads();

  // coalesced store: thread (p = tid>>4, t16 = tid&15) writes n = nb + 4*t16 .. +3
  {
    int p = tid >> 4, t16 = tid & 15;
    float4 v;
    v.x = trans[t16 * 260 + 0 * 65 + p];
    v.y = trans[t16 * 260 + 1 * 65 + p];
    v.z = trans[t16 * 260 + 2 * 65 + p];
    v.w = trans[t16 * 260 + 3 * 65 + p];
    *(float4*)(out + ((size_t)b * 64 + p) * NPTS + nb + 4 * t16) = v;
  }
}

extern "C" void kernel_launch(void* const* d_in, const int* in_sizes, int n_in,
                              void* d_out, int out_size, void* d_ws, size_t ws_size,
                              hipStream_t stream) {
  (void)in_sizes; (void)n_in; (void)out_size; (void)ws_size;
  const float* pos = (const float*)d_in[0];
  const float* w1  = (const float*)d_in[1];
  const float* b1  = (const float*)d_in[2];
  const float* w2  = (const float*)d_in[3];
  const float* b2  = (const float*)d_in[4];
  float* out = (float*)d_out;

  // workspace: Wn (30*64 f32) then bb (64 f32)
  float* wn = (float*)d_ws;
  float* bb = (float*)((char*)d_ws + 30 * 64 * 4);

  prep_kernel<<<dim3(1), dim3(256), 0, stream>>>(w1, b1, w2, b2, wn, bb);
  topk_kernel<<<dim3(64, 8), dim3(1024), 0, stream>>>(pos, wn, bb, out);
}